// Round 5
// baseline (44707.501 us; speedup 1.0000x reference)
//
#include <hip/hip_runtime.h>
#include <hip/hip_bf16.h>
#include <cstdint>
#include <cstddef>

#define D    768
#define G3   2304
#define BS   64
#define SEQ  300
#define TDEC 100

typedef unsigned int u32;
typedef unsigned long long u64;

__device__ __forceinline__ float sigf(float x) { return 1.0f / (1.0f + __expf(-x)); }
__device__ __forceinline__ float tanhfast(float x) {
    float e = __expf(2.0f * x);
    return 1.0f - 2.0f / (e + 1.0f);
}
__device__ __forceinline__ void bf2x(u32 u, float& a, float& b) {
    union { u32 i; float f; } xx, yy;
    xx.i = u << 16; yy.i = u & 0xffff0000u; a = xx.f; b = yy.f;
}

// ---- device-scope (cross-XCD coherent) accessors: bypass L1/L2, no cache fences ----
__device__ __forceinline__ u64 dev_load_u64(const void* p) {
    return __hip_atomic_load((const u64*)p, __ATOMIC_RELAXED, __HIP_MEMORY_SCOPE_AGENT);
}
__device__ __forceinline__ void dev_store_u64(void* p, u64 v) {
    __hip_atomic_store((u64*)p, v, __ATOMIC_RELAXED, __HIP_MEMORY_SCOPE_AGENT);
}
__device__ __forceinline__ float dev_load_f32(const float* p) {
    u32 v = __hip_atomic_load((const u32*)p, __ATOMIC_RELAXED, __HIP_MEMORY_SCOPE_AGENT);
    union { u32 i; float f; } c; c.i = v; return c.f;
}
__device__ __forceinline__ void dev_store_f32(float* p, float v) {
    union { u32 i; float f; } c; c.f = v;
    __hip_atomic_store((u32*)p, c.i, __ATOMIC_RELAXED, __HIP_MEMORY_SCOPE_AGENT);
}
__device__ __forceinline__ void dev_atomic_add_f32(float* p, float v) {
    __hip_atomic_fetch_add(p, v, __ATOMIC_RELAXED, __HIP_MEMORY_SCOPE_AGENT);
}

// ---- grid barrier: NO cache-maintenance fences. Data moves via device-scope ops;
// the pre-barrier __syncthreads drains each wave's outstanding stores (compiler
// emits s_waitcnt vmcnt(0) before s_barrier).
__device__ __forceinline__ void pbar(u32* cnt, u32& tgt, u32 nblk) {
    __syncthreads();
    tgt += nblk;
    if (threadIdx.x == 0) {
        __builtin_amdgcn_s_waitcnt(0);
        __hip_atomic_fetch_add(cnt, 1u, __ATOMIC_RELAXED, __HIP_MEMORY_SCOPE_AGENT);
        while (__hip_atomic_load(cnt, __ATOMIC_RELAXED, __HIP_MEMORY_SCOPE_AGENT) < tgt)
            __builtin_amdgcn_s_sleep(2);
    }
    __syncthreads();
}

#define DOT4(acc, wv, x0, x1, x2, x3) \
    acc = fmaf((wv).x,(x0), fmaf((wv).y,(x1), fmaf((wv).z,(x2), fmaf((wv).w,(x3),(acc)))))

// ---------------- kPrep: dec_Wih split, init h/ctx/se/last/out/cnt ----------------
__global__ __launch_bounds__(256) void kPrep(
    const float* __restrict__ decWih, const float* __restrict__ tb,
    float* __restrict__ Wc, float* __restrict__ W0,
    float* __restrict__ hE0, float* __restrict__ hD0,
    float* __restrict__ ctx0, float* __restrict__ ctx1,
    float* __restrict__ se0, float* __restrict__ se1,
    float* __restrict__ lastP, float* __restrict__ out, u32* __restrict__ cnt)
{
    const int NW = G3 * 769;         // 1771776
    const int NH = D * 64;           // 49152
    const int NL = (TDEC + 1) * 64;
    const int NO = 64 * TDEC;
    const int TOT = NW + 4 * NH + 128 + NL + NO + 128;
    const float tbv = tb[0];
    const int stride = gridDim.x * blockDim.x;
    for (int u = blockIdx.x * blockDim.x + threadIdx.x; u < TOT; u += stride) {
        if (u < NW) {
            int g = u / 769; int c = u % 769;
            float w = decWih[u];
            if (c == 0) W0[g] = w; else Wc[(size_t)g * D + (c - 1)] = w;
        } else if (u < NW + NH) {
            hE0[u - NW] = 0.0f;
        } else if (u < NW + 2 * NH) {
            hD0[u - NW - NH] = 0.0f;
        } else if (u < NW + 3 * NH) {
            ctx0[u - NW - 2 * NH] = 0.0f;
        } else if (u < NW + 4 * NH) {
            ctx1[u - NW - 3 * NH] = 0.0f;
        } else if (u < NW + 4 * NH + 128) {
            int i = u - NW - 4 * NH;
            if (i < 64) se0[i] = 0.0f; else se1[i - 64] = 0.0f;
        } else if (u < NW + 4 * NH + 128 + NL) {
            int i = u - NW - 4 * NH - 128;
            lastP[i] = (i < 64) ? 0.0f : tbv;   // preds accumulate, seeded with tb
        } else if (u < NW + 4 * NH + 128 + NL + NO) {
            out[u - NW - 4 * NH - 128 - NL] = tbv;
        } else {
            cnt[u - NW - 4 * NH - 128 - NL - NO] = 0u;
        }
    }
}

// ---------------- kPE: gpe[t][n] = pe[t,:] . Wih[n,:]  (fp32 out) ----------------
// grid (36 n-tiles, 5 t-tiles), 64x64 tile, K-chunk 16; PE computed on the fly
__global__ __launch_bounds__(256) void kPE(
    const float* __restrict__ Wih, float* __restrict__ gpe)
{
    __shared__ float As[16 * 64];
    __shared__ float Bs[16 * 64];
    const int tid = threadIdx.x;
    const int n0 = blockIdx.x * 64;
    const int t0 = blockIdx.y * 64;
    const int lr = tid >> 2;
    const int lk = (tid & 3) * 4;
    const int tm = (tid >> 4) * 4;   // t-quad
    const int tn = (tid & 15) * 4;   // n-quad

    float acc[4][4];
    #pragma unroll
    for (int i = 0; i < 4; ++i)
        #pragma unroll
        for (int j = 0; j < 4; ++j) acc[i][j] = 0.f;

    const int t = t0 + lr;
    const float tf = (float)t;
    for (int kc = 0; kc < D; kc += 16) {
        const float4 a4 = *(const float4*)(Wih + (size_t)(n0 + lr) * D + kc + lk);
        float4 b4 = make_float4(0.f, 0.f, 0.f, 0.f);
        if (t < SEQ) {
            const int i0 = (kc + lk) >> 1;
            const float dv0 = __expf(-0.0239852614f * (float)i0);
            const float dv1 = __expf(-0.0239852614f * (float)(i0 + 1));
            float s0, c0, s1, c1;
            __sincosf(tf * dv0, &s0, &c0);
            __sincosf(tf * dv1, &s1, &c1);
            b4 = make_float4(s0, c0, s1, c1);
        }
        As[(lk + 0) * 64 + lr] = a4.x; As[(lk + 1) * 64 + lr] = a4.y;
        As[(lk + 2) * 64 + lr] = a4.z; As[(lk + 3) * 64 + lr] = a4.w;
        Bs[(lk + 0) * 64 + lr] = b4.x; Bs[(lk + 1) * 64 + lr] = b4.y;
        Bs[(lk + 2) * 64 + lr] = b4.z; Bs[(lk + 3) * 64 + lr] = b4.w;
        __syncthreads();
        #pragma unroll
        for (int k = 0; k < 16; ++k) {
            const float4 bv = *(const float4*)(Bs + k * 64 + tm);  // t-dim
            const float4 av = *(const float4*)(As + k * 64 + tn);  // n-dim
            acc[0][0] = fmaf(bv.x, av.x, acc[0][0]); acc[0][1] = fmaf(bv.x, av.y, acc[0][1]);
            acc[0][2] = fmaf(bv.x, av.z, acc[0][2]); acc[0][3] = fmaf(bv.x, av.w, acc[0][3]);
            acc[1][0] = fmaf(bv.y, av.x, acc[1][0]); acc[1][1] = fmaf(bv.y, av.y, acc[1][1]);
            acc[1][2] = fmaf(bv.y, av.z, acc[1][2]); acc[1][3] = fmaf(bv.y, av.w, acc[1][3]);
            acc[2][0] = fmaf(bv.z, av.x, acc[2][0]); acc[2][1] = fmaf(bv.z, av.y, acc[2][1]);
            acc[2][2] = fmaf(bv.z, av.z, acc[2][2]); acc[2][3] = fmaf(bv.z, av.w, acc[2][3]);
            acc[3][0] = fmaf(bv.w, av.x, acc[3][0]); acc[3][1] = fmaf(bv.w, av.y, acc[3][1]);
            acc[3][2] = fmaf(bv.w, av.z, acc[3][2]); acc[3][3] = fmaf(bv.w, av.w, acc[3][3]);
        }
        __syncthreads();
    }
    #pragma unroll
    for (int i = 0; i < 4; ++i) {
        const int tt = t0 + tm + i;
        if (tt < SEQ) {
            float4 v = make_float4(acc[i][0], acc[i][1], acc[i][2], acc[i][3]);
            *(float4*)(gpe + (size_t)tt * G3 + n0 + tn) = v;
        }
    }
}

// ---------------- kEncP: persistent encoder (192 blocks x 256, 300 steps) ----------------
// thread: b = lane, j = blk*4 + wave. gi computed in-step from x (cached) + gpe.
__global__ __launch_bounds__(256) void kEncP(
    const float* __restrict__ x, const float* __restrict__ gpe,
    const float* __restrict__ Wih, const float* __restrict__ Whh,
    const float* __restrict__ bih, const float* __restrict__ bhh,
    float* __restrict__ hE0, float* __restrict__ hE1,
    __hip_bfloat16* __restrict__ encB, u32* __restrict__ cnt)
{
    __shared__ float lds_h[64 * 64];   // [kk][b]
    const int tid = threadIdx.x;
    const int b   = tid & 63;
    const int jw  = __builtin_amdgcn_readfirstlane((int)(blockIdx.x * 4 + (tid >> 6)));

    const float* wir = Wih + (size_t)jw * D;
    const float* wiz = Wih + (size_t)(768 + jw) * D;
    const float* win = Wih + (size_t)(1536 + jw) * D;
    const float* whr = Whh + (size_t)jw * D;
    const float* whz = Whh + (size_t)(768 + jw) * D;
    const float* whn = Whh + (size_t)(1536 + jw) * D;
    const float bir = bih[jw] + bhh[jw];
    const float biz = bih[768 + jw] + bhh[768 + jw];
    const float bin_ = bih[1536 + jw];
    const float bhn  = bhh[1536 + jw];
    const float* xrow = x + (size_t)b * SEQ * D;

    u32 tgt = 0;
    for (int t = 0; t < SEQ; ++t) {
        const float* hr = (t & 1) ? hE1 : hE0;
        float*       hw = (t & 1) ? hE0 : hE1;

        // gi = x[b,t,:] . Wih rows (weights via uniform s_loads, x cached/L3-warm)
        float air = 0.f, aiz = 0.f, ain = 0.f;
        const float* xt = xrow + (size_t)t * D;
        for (int kc = 0; kc < D; kc += 4) {
            const float4 xa = *(const float4*)(xt + kc);
            const float4 w0 = *(const float4*)(wir + kc);
            const float4 w1 = *(const float4*)(wiz + kc);
            const float4 w2 = *(const float4*)(win + kc);
            DOT4(air, w0, xa.x, xa.y, xa.z, xa.w);
            DOT4(aiz, w1, xa.x, xa.y, xa.z, xa.w);
            DOT4(ain, w2, xa.x, xa.y, xa.z, xa.w);
        }

        // gh = h . Whh rows (h staged via device-scope loads)
        float ahr = 0.f, ahz = 0.f, ahn = 0.f;
        for (int kc = 0; kc < D; kc += 64) {
            u64* lh64 = (u64*)lds_h;
            const u64* gh64 = (const u64*)(hr + kc * 64);
            #pragma unroll
            for (int i = 0; i < 8; ++i) lh64[tid + 256 * i] = dev_load_u64(gh64 + tid + 256 * i);
            __syncthreads();
            #pragma unroll
            for (int kk = 0; kk < 64; kk += 4) {
                const float4 v3 = *(const float4*)(whr + kc + kk);
                const float4 v4 = *(const float4*)(whz + kc + kk);
                const float4 v5 = *(const float4*)(whn + kc + kk);
                const float h0 = lds_h[(kk + 0) * 64 + b];
                const float h1 = lds_h[(kk + 1) * 64 + b];
                const float h2 = lds_h[(kk + 2) * 64 + b];
                const float h3 = lds_h[(kk + 3) * 64 + b];
                DOT4(ahr, v3, h0, h1, h2, h3);
                DOT4(ahz, v4, h0, h1, h2, h3);
                DOT4(ahn, v5, h0, h1, h2, h3);
            }
            __syncthreads();
        }
        const float gp0 = gpe[(size_t)t * G3 + jw];
        const float gp1 = gpe[(size_t)t * G3 + 768 + jw];
        const float gp2 = gpe[(size_t)t * G3 + 1536 + jw];
        const float r = sigf(air + gp0 + ahr + bir);
        const float z = sigf(aiz + gp1 + ahz + biz);
        const float n = tanhfast(ain + gp2 + bin_ + r * (ahn + bhn));
        const float ho = lds_h[0];  // placeholder (not used); real ho below
        (void)ho;
        const float hov = dev_load_f32(hr + jw * 64 + b);
        const float hn = (1.f - z) * n + z * hov;
        dev_store_f32(hw + jw * 64 + b, hn);
        encB[((size_t)b * SEQ + t) * D + jw] = __float2bfloat16(hn);
        pbar(cnt, tgt, 192);
    }
}

// ---------------- kGemmMem: mem = enc @ mW^T + mb  (bf16 A, fp32 B, bf16 out) ----------------
__global__ __launch_bounds__(256) void kGemmMem(
    const __hip_bfloat16* __restrict__ encB, const float* __restrict__ mW,
    const float* __restrict__ mb, __hip_bfloat16* __restrict__ memB)
{
    __shared__ float As[16 * 64];
    __shared__ float Bs[16 * 64];
    const int tid = threadIdx.x;
    const int m0 = blockIdx.y * 64, n0 = blockIdx.x * 64;
    const int lr = tid >> 2;
    const int lk = (tid & 3) * 4;
    const int tm = (tid >> 4) * 4;
    const int tn = (tid & 15) * 4;

    float acc[4][4];
    #pragma unroll
    for (int i = 0; i < 4; ++i)
        #pragma unroll
        for (int j = 0; j < 4; ++j) acc[i][j] = 0.f;

    for (int kc = 0; kc < D; kc += 16) {
        const uint2 ua = *(const uint2*)(encB + (size_t)(m0 + lr) * D + kc + lk);
        float a0, a1, a2, a3;
        bf2x(ua.x, a0, a1); bf2x(ua.y, a2, a3);
        const float4 b4 = *(const float4*)(mW + (size_t)(n0 + lr) * D + kc + lk);
        As[(lk + 0) * 64 + lr] = a0; As[(lk + 1) * 64 + lr] = a1;
        As[(lk + 2) * 64 + lr] = a2; As[(lk + 3) * 64 + lr] = a3;
        Bs[(lk + 0) * 64 + lr] = b4.x; Bs[(lk + 1) * 64 + lr] = b4.y;
        Bs[(lk + 2) * 64 + lr] = b4.z; Bs[(lk + 3) * 64 + lr] = b4.w;
        __syncthreads();
        #pragma unroll
        for (int k = 0; k < 16; ++k) {
            const float4 av = *(const float4*)(As + k * 64 + tm);
            const float4 bv = *(const float4*)(Bs + k * 64 + tn);
            acc[0][0] = fmaf(av.x, bv.x, acc[0][0]); acc[0][1] = fmaf(av.x, bv.y, acc[0][1]);
            acc[0][2] = fmaf(av.x, bv.z, acc[0][2]); acc[0][3] = fmaf(av.x, bv.w, acc[0][3]);
            acc[1][0] = fmaf(av.y, bv.x, acc[1][0]); acc[1][1] = fmaf(av.y, bv.y, acc[1][1]);
            acc[1][2] = fmaf(av.y, bv.z, acc[1][2]); acc[1][3] = fmaf(av.y, bv.w, acc[1][3]);
            acc[2][0] = fmaf(av.z, bv.x, acc[2][0]); acc[2][1] = fmaf(av.z, bv.y, acc[2][1]);
            acc[2][2] = fmaf(av.z, bv.z, acc[2][2]); acc[2][3] = fmaf(av.z, bv.w, acc[2][3]);
            acc[3][0] = fmaf(av.w, bv.x, acc[3][0]); acc[3][1] = fmaf(av.w, bv.y, acc[3][1]);
            acc[3][2] = fmaf(av.w, bv.z, acc[3][2]); acc[3][3] = fmaf(av.w, bv.w, acc[3][3]);
        }
        __syncthreads();
    }
    const float bb0 = mb[n0 + tn + 0], bb1 = mb[n0 + tn + 1];
    const float bb2 = mb[n0 + tn + 2], bb3 = mb[n0 + tn + 3];
    #pragma unroll
    for (int i = 0; i < 4; ++i) {
        __hip_bfloat16* row = memB + (size_t)(m0 + tm + i) * D + n0 + tn;
        row[0] = __float2bfloat16(acc[i][0] + bb0);
        row[1] = __float2bfloat16(acc[i][1] + bb1);
        row[2] = __float2bfloat16(acc[i][2] + bb2);
        row[3] = __float2bfloat16(acc[i][3] + bb3);
    }
}

// ---------------- kDecP: persistent decoder (256 blocks x 256, 100 steps x 3 phases) ----------------
__global__ __launch_bounds__(256) void kDecP(
    const float* __restrict__ qW, const float* __restrict__ qb,
    const __hip_bfloat16* __restrict__ memB, const __hip_bfloat16* __restrict__ encB,
    const float* __restrict__ pW, const float* __restrict__ pb,
    const float* __restrict__ dWhh, const float* __restrict__ Wc, const float* __restrict__ W0,
    const float* __restrict__ dbih, const float* __restrict__ dbhh,
    const float* __restrict__ tW, const float* __restrict__ tb,
    float* __restrict__ hD0, float* __restrict__ hD1,
    float* __restrict__ qT, float* __restrict__ ctx0, float* __restrict__ ctx1,
    float* __restrict__ se0, float* __restrict__ se1,
    float* __restrict__ lastP, float* __restrict__ out, u32* __restrict__ cnt)
{
    __shared__ float lds[8192];     // 32 KB, phase-dependent usage
    const int tid = threadIdx.x;
    const int blk = blockIdx.x;
    const int b   = tid & 63;
    u32 tgt = 0;

    const int jw = __builtin_amdgcn_readfirstlane((int)((blk & 255) * 4 + (tid >> 6)) & 0x7ff) % 768;
    // (jw only meaningful for blk<192; computed uniformly to keep SGPR allocation simple)
    const int jq = __builtin_amdgcn_readfirstlane((int)(blk * 4 + (tid >> 6)));

    for (int t = 0; t < TDEC; ++t) {
        const float* hr = (t & 1) ? hD1 : hD0;
        float*       hw = (t & 1) ? hD0 : hD1;
        float* ctxCur = (t & 1) ? ctx1 : ctx0;
        float* ctxNxt = (t & 1) ? ctx0 : ctx1;
        float* seCur  = (t & 1) ? se1 : se0;
        float* seNxt  = (t & 1) ? se0 : se1;

        // ---- Phase Q: blk<192 compute q; blk>=192 zero next ctx/se ----
        if (blk < 192) {
            const float* w = qW + (size_t)jq * D;
            float acc = 0.f;
            for (int kc = 0; kc < D; kc += 64) {
                u64* lh64 = (u64*)lds;
                const u64* gh64 = (const u64*)(hr + kc * 64);
                #pragma unroll
                for (int i = 0; i < 8; ++i) lh64[tid + 256 * i] = dev_load_u64(gh64 + tid + 256 * i);
                __syncthreads();
                #pragma unroll
                for (int kk = 0; kk < 64; kk += 4) {
                    const float4 w4 = *(const float4*)(w + kc + kk);
                    acc = fmaf(w4.x, lds[(kk + 0) * 64 + b], acc);
                    acc = fmaf(w4.y, lds[(kk + 1) * 64 + b], acc);
                    acc = fmaf(w4.z, lds[(kk + 2) * 64 + b], acc);
                    acc = fmaf(w4.w, lds[(kk + 3) * 64 + b], acc);
                }
                __syncthreads();
            }
            acc += qb[jq];
            // transpose in LDS -> write qT[b][j] (b-major), 4 consecutive j per block
            lds[b * 4 + (tid >> 6)] = acc;
            __syncthreads();
            if (tid < 128) {
                const int r = tid >> 1, hf = tid & 1;
                float2 v = *(float2*)(lds + r * 4 + hf * 2);
                union { float2 f; u64 u; } c; c.f = v;
                dev_store_u64(qT + (size_t)r * D + jq /*base j of wave0*/ - (tid >> 6) * 0 /*noop*/
                              - ((int)(tid >> 6)) * 0 + (blk * 4 - jq) + jq - (blk * 4) + blk * 4 + hf * 2, c.u);
            }
            __syncthreads();
        } else {
            // zero ctxNxt (49152 floats over 64 blocks) and seNxt
            const int base = (blk - 192) * 768;
            for (int i = tid; i < 768; i += 256) dev_store_f32(ctxNxt + base + i, 0.f);
            if (blk == 192 && tid < 64) dev_store_f32(seNxt + tid, 0.f);
        }
        pbar(cnt, tgt, 256);

        // ---- Phase A: attention, all 256 blocks; (b, ch = blk>>6) 75 rows ----
        {
            const int ab = blk & 63;
            const int ch = blk >> 6;
            const int s0 = ch * 75;
            float* s_q  = lds;
            float* s_pw = lds + 768;
            float* s_cx = lds + 1536;
            float* s_se = lds + 2304;
            for (int i = tid; i < 384; i += 256) {
                union { u64 u; float2 f; } c;
                c.u = dev_load_u64(qT + (size_t)ab * D + 2 * i);
                s_q[2 * i] = c.f.x; s_q[2 * i + 1] = c.f.y;
            }
            for (int i = tid; i < 768; i += 256) { s_pw[i] = pW[i]; s_cx[i] = 0.f; }
            if (tid == 0) s_se[0] = 0.f;
            __syncthreads();
            const int lane = tid & 63;
            const int wv   = tid >> 6;
            float cacc[12];
            #pragma unroll
            for (int i = 0; i < 12; ++i) cacc[i] = 0.f;
            float seacc = 0.f;
            const float pbv = pb[0];
            for (int s = s0 + wv; s < s0 + 75; s += 4) {
                const __hip_bfloat16* mrow = memB + ((size_t)ab * SEQ + s) * D;
                const __hip_bfloat16* erow = encB + ((size_t)ab * SEQ + s) * D;
                float lp = 0.f;
                #pragma unroll
                for (int g = 0; g < 3; ++g) {
                    const int d0 = g * 256 + lane * 4;
                    const uint2 mu = *(const uint2*)(mrow + d0);
                    float m0, m1, m2, m3;
                    bf2x(mu.x, m0, m1); bf2x(mu.y, m2, m3);
                    const float4 qv = *(const float4*)(s_q + d0);
                    const float4 pv = *(const float4*)(s_pw + d0);
                    lp = fmaf(pv.x, tanhfast(m0 + qv.x), lp);
                    lp = fmaf(pv.y, tanhfast(m1 + qv.y), lp);
                    lp = fmaf(pv.z, tanhfast(m2 + qv.z), lp);
                    lp = fmaf(pv.w, tanhfast(m3 + qv.w), lp);
                }
                #pragma unroll
                for (int o = 32; o > 0; o >>= 1) lp += __shfl_xor(lp, o, 64);
                const float e = __expf(lp + pbv);    // identical on all 64 lanes
                seacc += e;
                #pragma unroll
                for (int g = 0; g < 3; ++g) {
                    const int d0 = g * 256 + lane * 4;
                    const uint2 eu = *(const uint2*)(erow + d0);
                    float e0, e1, e2, e3;
                    bf2x(eu.x, e0, e1); bf2x(eu.y, e2, e3);
                    cacc[g * 4 + 0] = fmaf(e, e0, cacc[g * 4 + 0]);
                    cacc[g * 4 + 1] = fmaf(e, e1, cacc[g * 4 + 1]);
                    cacc[g * 4 + 2] = fmaf(e, e2, cacc[g * 4 + 2]);
                    cacc[g * 4 + 3] = fmaf(e, e3, cacc[g * 4 + 3]);
                }
            }
            #pragma unroll
            for (int g = 0; g < 3; ++g) {
                const int d0 = g * 256 + lane * 4;
                atomicAdd(&s_cx[d0 + 0], cacc[g * 4 + 0]);
                atomicAdd(&s_cx[d0 + 1], cacc[g * 4 + 1]);
                atomicAdd(&s_cx[d0 + 2], cacc[g * 4 + 2]);
                atomicAdd(&s_cx[d0 + 3], cacc[g * 4 + 3]);
            }
            if (lane == 0) atomicAdd(&s_se[0], seacc);
            __syncthreads();
            // ctx[k][b] combine via device-scope atomics (4 contenders per address)
            for (int i = tid; i < 768; i += 256) dev_atomic_add_f32(ctxCur + (size_t)i * 64 + ab, s_cx[i]);
            if (tid == 0) dev_atomic_add_f32(seCur + ab, s_se[0]);
        }
        pbar(cnt, tgt, 256);

        // ---- Phase C: GRU cell + pred, blk<192 ----
        if (blk < 192) {
            float* lds_h = lds;            // [kk][b]
            float* lds_c = lds + 4096;     // [kk][b]
            const float* whr = dWhh + (size_t)jq * D;
            const float* whz = dWhh + (size_t)(768 + jq) * D;
            const float* whn = dWhh + (size_t)(1536 + jq) * D;
            const float* wcr = Wc + (size_t)jq * D;
            const float* wcz = Wc + (size_t)(768 + jq) * D;
            const float* wcn = Wc + (size_t)(1536 + jq) * D;
            float cir = 0.f, ciz = 0.f, cin_ = 0.f, ahr = 0.f, ahz = 0.f, ahn = 0.f;
            for (int kc = 0; kc < D; kc += 64) {
                u64* lh64 = (u64*)lds_h;
                u64* lc64 = (u64*)lds_c;
                const u64* gh64 = (const u64*)(hr + kc * 64);
                const u64* gc64 = (const u64*)(ctxCur + kc * 64);
                #pragma unroll
                for (int i = 0; i < 8; ++i) {
                    lh64[tid + 256 * i] = dev_load_u64(gh64 + tid + 256 * i);
                    lc64[tid + 256 * i] = dev_load_u64(gc64 + tid + 256 * i);
                }
                __syncthreads();
                #pragma unroll
                for (int kk = 0; kk < 64; kk += 4) {
                    const float4 v0 = *(const float4*)(wcr + kc + kk);
                    const float4 v1 = *(const float4*)(wcz + kc + kk);
                    const float4 v2 = *(const float4*)(wcn + kc + kk);
                    const float4 v3 = *(const float4*)(whr + kc + kk);
                    const float4 v4 = *(const float4*)(whz + kc + kk);
                    const float4 v5 = *(const float4*)(whn + kc + kk);
                    const float c0 = lds_c[(kk + 0) * 64 + b];
                    const float c1 = lds_c[(kk + 1) * 64 + b];
                    const float c2 = lds_c[(kk + 2) * 64 + b];
                    const float c3 = lds_c[(kk + 3) * 64 + b];
                    const float h0 = lds_h[(kk + 0) * 64 + b];
                    const float h1 = lds_h[(kk + 1) * 64 + b];
                    const float h2 = lds_h[(kk + 2) * 64 + b];
                    const float h3 = lds_h[(kk + 3) * 64 + b];
                    DOT4(cir, v0, c0, c1, c2, c3);
                    DOT4(ciz, v1, c0, c1, c2, c3);
                    DOT4(cin_, v2, c0, c1, c2, c3);
                    DOT4(ahr, v3, h0, h1, h2, h3);
                    DOT4(ahz, v4, h0, h1, h2, h3);
                    DOT4(ahn, v5, h0, h1, h2, h3);
                }
                __syncthreads();
            }
            const float se = dev_load_f32(seCur + b);
            const float inv = 1.f / se;
            const float lst = dev_load_f32(lastP + (size_t)t * 64 + b);
            const float gir = cir * inv + W0[jq] * lst + dbih[jq];
            const float giz = ciz * inv + W0[768 + jq] * lst + dbih[768 + jq];
            const float gin = cin_ * inv + W0[1536 + jq] * lst + dbih[1536 + jq];
            const float r = sigf(gir + ahr + dbhh[jq]);
            const float z = sigf(giz + ahz + dbhh[768 + jq]);
            const float n = tanhfast(gin + r * (ahn + dbhh[1536 + jq]));
            const float hov = dev_load_f32(hr + jq * 64 + b);
            const float hn = (1.f - z) * n + z * hov;
            dev_store_f32(hw + jq * 64 + b, hn);

            // pred partial: out[b][t] += sum_j tW[j]*hn  (out & lastP seeded with tb)
            __syncthreads();
            lds[(tid >> 6) * 64 + b] = tW[jq] * hn;
            __syncthreads();
            if (tid < 64) {
                const float p = lds[tid] + lds[64 + tid] + lds[128 + tid] + lds[192 + tid];
                atomicAdd(&out[(size_t)tid * TDEC + t], p);
                dev_atomic_add_f32(lastP + (size_t)(t + 1) * 64 + tid, p);
            }
        }
        pbar(cnt, tgt, 256);
    }
}

// ---------------- launch ----------------
extern "C" void kernel_launch(void* const* d_in, const int* in_sizes, int n_in,
                              void* d_out, int out_size, void* d_ws, size_t ws_size,
                              hipStream_t stream) {
    const float* x    = (const float*)d_in[0];
    const float* eWih = (const float*)d_in[1];
    const float* eWhh = (const float*)d_in[2];
    const float* ebih = (const float*)d_in[3];
    const float* ebhh = (const float*)d_in[4];
    const float* dWih = (const float*)d_in[5];
    const float* dWhh = (const float*)d_in[6];
    const float* dbih = (const float*)d_in[7];
    const float* dbhh = (const float*)d_in[8];
    const float* qW   = (const float*)d_in[9];
    const float* qb   = (const float*)d_in[10];
    const float* mW   = (const float*)d_in[11];
    const float* mb   = (const float*)d_in[12];
    const float* pW   = (const float*)d_in[13];
    const float* pb   = (const float*)d_in[14];
    const float* tW   = (const float*)d_in[15];
    const float* tb   = (const float*)d_in[16];
    float* out = (float*)d_out;

    char* w = (char*)d_ws;
    auto alloc = [&](size_t bytes) -> char* {
        char* p = w; w += (bytes + 255) & ~(size_t)255; return p;
    };
    // total ~71 MB
    float* Wc    = (float*)alloc((size_t)G3 * D * 4);
    float* W0    = (float*)alloc((size_t)G3 * 4);
    __hip_bfloat16* encB = (__hip_bfloat16*)alloc((size_t)BS * SEQ * D * 2);
    __hip_bfloat16* memB = (__hip_bfloat16*)alloc((size_t)BS * SEQ * D * 2);
    float* gpe   = (float*)alloc((size_t)SEQ * G3 * 4);
    float* hE0   = (float*)alloc((size_t)D * 64 * 4);
    float* hE1   = (float*)alloc((size_t)D * 64 * 4);
    float* hD0   = (float*)alloc((size_t)D * 64 * 4);
    float* hD1   = (float*)alloc((size_t)D * 64 * 4);
    float* qT    = (float*)alloc((size_t)BS * D * 4);
    float* ctx0  = (float*)alloc((size_t)D * 64 * 4);
    float* ctx1  = (float*)alloc((size_t)D * 64 * 4);
    float* se0   = (float*)alloc(256);
    float* se1   = (float*)alloc(256);
    float* lastP = (float*)alloc((TDEC + 1) * 64 * 4);
    u32*   cnt   = (u32*)  alloc(128 * sizeof(u32));

    kPrep<<<512, 256, 0, stream>>>(dWih, tb, Wc, W0, hE0, hD0, ctx0, ctx1,
                                   se0, se1, lastP, out, cnt);
    kPE<<<dim3(36, 5), 256, 0, stream>>>(eWih, gpe);
    kEncP<<<192, 256, 0, stream>>>(x, gpe, eWih, eWhh, ebih, ebhh, hE0, hE1, encB, cnt + 0);
    kGemmMem<<<dim3(12, 300), 256, 0, stream>>>(encB, mW, mb, memB);
    kDecP<<<256, 256, 0, stream>>>(qW, qb, memB, encB, pW, pb, dWhh, Wc, W0, dbih, dbhh,
                                   tW, tb, hD0, hD1, qT, ctx0, ctx1, se0, se1,
                                   lastP, out, cnt + 64);
}

// Round 6
// 28869.678 us; speedup vs baseline: 1.5486x; 1.5486x over previous
//
#include <hip/hip_runtime.h>
#include <hip/hip_bf16.h>
#include <cstdint>
#include <cstddef>

#define D    768
#define G3   2304
#define BS   64
#define SEQ  300
#define TDEC 100
#define CH   50      // encoder chunk (6 chunks)

typedef unsigned int u32;
typedef unsigned long long u64;

__device__ __forceinline__ float sigf(float x) { return 1.0f / (1.0f + __expf(-x)); }
__device__ __forceinline__ float tanhfast(float x) {
    float e = __expf(2.0f * x);
    return 1.0f - 2.0f / (e + 1.0f);
}
__device__ __forceinline__ void bf2x(u32 u, float& a, float& b) {
    union { u32 i; float f; } xx, yy;
    xx.i = u << 16; yy.i = u & 0xffff0000u; a = xx.f; b = yy.f;
}
__device__ __forceinline__ float bfu(u64 e, int r) {
    union { u32 i; float f; } c; c.i = ((u32)(e >> (16 * r)) & 0xffffu) << 16; return c.f;
}

// device-scope (cross-XCD) accessors — validated in R5 (passed)
__device__ __forceinline__ u64 dev_load_u64(const u64* p) {
    return __hip_atomic_load(p, __ATOMIC_RELAXED, __HIP_MEMORY_SCOPE_AGENT);
}
__device__ __forceinline__ void dev_store_u64(u64* p, u64 v) {
    __hip_atomic_store(p, v, __ATOMIC_RELAXED, __HIP_MEMORY_SCOPE_AGENT);
}
__device__ __forceinline__ float dev_load_f32(const float* p) {
    u32 v = __hip_atomic_load((const u32*)p, __ATOMIC_RELAXED, __HIP_MEMORY_SCOPE_AGENT);
    union { u32 i; float f; } c; c.i = v; return c.f;
}
__device__ __forceinline__ void dev_store_f32(float* p, float v) {
    union { u32 i; float f; } c; c.f = v;
    __hip_atomic_store((u32*)p, c.i, __ATOMIC_RELAXED, __HIP_MEMORY_SCOPE_AGENT);
}
__device__ __forceinline__ void dev_atomic_add_f32(float* p, float v) {
    __hip_atomic_fetch_add(p, v, __ATOMIC_RELAXED, __HIP_MEMORY_SCOPE_AGENT);
}

// fence-free barrier, 8-way-split arrival counters (contention /8)
__device__ __forceinline__ void pbar(u32* cnt, u32& tgt, u32 nblk) {
    __syncthreads();                 // emits s_waitcnt vmcnt(0) per wave -> stores drained
    tgt += nblk;
    if (threadIdx.x == 0) {
        __hip_atomic_fetch_add(cnt + (blockIdx.x & 7), 1u, __ATOMIC_RELAXED, __HIP_MEMORY_SCOPE_AGENT);
        u32 s;
        do {
            s = 0;
            #pragma unroll
            for (int i = 0; i < 8; ++i)
                s += __hip_atomic_load(cnt + i, __ATOMIC_RELAXED, __HIP_MEMORY_SCOPE_AGENT);
            if (s < tgt) __builtin_amdgcn_s_sleep(1);
        } while (s < tgt);
    }
    __syncthreads();
}

#define DOT4(acc, wv, x0, x1, x2, x3) \
    acc = fmaf((wv).x,(x0), fmaf((wv).y,(x1), fmaf((wv).z,(x2), fmaf((wv).w,(x3),(acc)))))

// ---------------- gi tile: gi[tc][j][b] = (x[b,t,:]+pe[t,:]) . Wih[j,:]  (bf16) ----------------
// 256 threads, 64x64 output tile, K-chunk 16, PE inline (R4-proven)
__device__ void giTile(const float* __restrict__ x, const float* __restrict__ Wih,
                       __hip_bfloat16* __restrict__ giOut, int t, int tc, int j0,
                       float* As, float* Bs, int tid)
{
    const int lr = tid >> 2;
    const int lk = (tid & 3) * 4;
    const int tm = (tid >> 4) * 4;
    const int tn = (tid & 15) * 4;
    const float tf = (float)t;
    float acc[4][4];
    #pragma unroll
    for (int i = 0; i < 4; ++i)
        #pragma unroll
        for (int j = 0; j < 4; ++j) acc[i][j] = 0.f;

    for (int kc = 0; kc < D; kc += 16) {
        const float4 a4 = *(const float4*)(Wih + (size_t)(j0 + lr) * D + kc + lk);
        float4 b4 = *(const float4*)(x + ((size_t)lr * SEQ + t) * D + kc + lk);
        const int i0 = (kc + lk) >> 1;
        const float dv0 = __expf(-0.0239852614f * (float)i0);
        const float dv1 = __expf(-0.0239852614f * (float)(i0 + 1));
        float s0, c0, s1, c1;
        __sincosf(tf * dv0, &s0, &c0);
        __sincosf(tf * dv1, &s1, &c1);
        b4.x += s0; b4.y += c0; b4.z += s1; b4.w += c1;
        As[(lk + 0) * 64 + lr] = a4.x; As[(lk + 1) * 64 + lr] = a4.y;
        As[(lk + 2) * 64 + lr] = a4.z; As[(lk + 3) * 64 + lr] = a4.w;
        Bs[(lk + 0) * 64 + lr] = b4.x; Bs[(lk + 1) * 64 + lr] = b4.y;
        Bs[(lk + 2) * 64 + lr] = b4.z; Bs[(lk + 3) * 64 + lr] = b4.w;
        __syncthreads();
        #pragma unroll
        for (int k = 0; k < 16; ++k) {
            const float4 av = *(const float4*)(As + k * 64 + tm);
            const float4 bv = *(const float4*)(Bs + k * 64 + tn);
            acc[0][0] = fmaf(av.x, bv.x, acc[0][0]); acc[0][1] = fmaf(av.x, bv.y, acc[0][1]);
            acc[0][2] = fmaf(av.x, bv.z, acc[0][2]); acc[0][3] = fmaf(av.x, bv.w, acc[0][3]);
            acc[1][0] = fmaf(av.y, bv.x, acc[1][0]); acc[1][1] = fmaf(av.y, bv.y, acc[1][1]);
            acc[1][2] = fmaf(av.y, bv.z, acc[1][2]); acc[1][3] = fmaf(av.y, bv.w, acc[1][3]);
            acc[2][0] = fmaf(av.z, bv.x, acc[2][0]); acc[2][1] = fmaf(av.z, bv.y, acc[2][1]);
            acc[2][2] = fmaf(av.z, bv.z, acc[2][2]); acc[2][3] = fmaf(av.z, bv.w, acc[2][3]);
            acc[3][0] = fmaf(av.w, bv.x, acc[3][0]); acc[3][1] = fmaf(av.w, bv.y, acc[3][1]);
            acc[3][2] = fmaf(av.w, bv.z, acc[3][2]); acc[3][3] = fmaf(av.w, bv.w, acc[3][3]);
        }
        __syncthreads();
    }
    #pragma unroll
    for (int i = 0; i < 4; ++i) {
        __hip_bfloat16* row = giOut + ((size_t)tc * G3 + j0 + tm + i) * 64 + tn;
        row[0] = __float2bfloat16(acc[i][0]);
        row[1] = __float2bfloat16(acc[i][1]);
        row[2] = __float2bfloat16(acc[i][2]);
        row[3] = __float2bfloat16(acc[i][3]);
    }
}

// ---------------- kPrep ----------------
__global__ __launch_bounds__(256) void kPrep(
    const float* __restrict__ decWih, const float* __restrict__ tb,
    float* __restrict__ Wc, float* __restrict__ W0,
    u64* __restrict__ hBe0, u64* __restrict__ hBe1,
    u64* __restrict__ hBd0, u64* __restrict__ hBd1,
    float* __restrict__ ctx0, float* __restrict__ se0, float* __restrict__ last0,
    float* __restrict__ out, u32* __restrict__ cnt)
{
    const int NW = G3 * 769;           // 1771776
    const int NB = 192 * 64;           // u64 entries per h-buffer
    const int TOT = NW + 4 * NB + (D * 64) + 64 + 64 + 64 * TDEC + 128;
    const float tbv = tb[0];
    const int stride = gridDim.x * blockDim.x;
    for (int u = blockIdx.x * blockDim.x + threadIdx.x; u < TOT; u += stride) {
        if (u < NW) {
            int g = u / 769; int c = u % 769;
            float w = decWih[u];
            if (c == 0) W0[g] = w; else Wc[(size_t)g * D + (c - 1)] = w;
        } else if (u < NW + NB) hBe0[u - NW] = 0ull;
        else if (u < NW + 2 * NB) hBe1[u - NW - NB] = 0ull;
        else if (u < NW + 3 * NB) hBd0[u - NW - 2 * NB] = 0ull;
        else if (u < NW + 4 * NB) hBd1[u - NW - 3 * NB] = 0ull;
        else if (u < NW + 4 * NB + D * 64) ctx0[u - NW - 4 * NB] = 0.f;
        else if (u < NW + 4 * NB + D * 64 + 64) se0[u - NW - 4 * NB - D * 64] = 0.f;
        else if (u < NW + 4 * NB + D * 64 + 128) last0[u - NW - 4 * NB - D * 64 - 64] = 0.f;
        else if (u < NW + 4 * NB + D * 64 + 128 + 64 * TDEC)
            out[u - NW - 4 * NB - D * 64 - 128] = tbv;
        else cnt[u - NW - 4 * NB - D * 64 - 128 - 64 * TDEC] = 0u;
    }
}

// ---------------- kGi0: standalone gi for chunk 0 ----------------
__global__ __launch_bounds__(256) void kGi0(
    const float* __restrict__ x, const float* __restrict__ Wih,
    __hip_bfloat16* __restrict__ giOut)
{
    __shared__ float lds[2048];
    giTile(x, Wih, giOut, blockIdx.y, blockIdx.y, blockIdx.x * 64, lds, lds + 1024, threadIdx.x);
}

// ---------------- kEncP: persistent encoder chunk (blocks 0..191 rec, 192..255 next-gi) ----------------
__global__ __launch_bounds__(256) void kEncP(
    const float* __restrict__ x, const float* __restrict__ Wih,
    const float* __restrict__ Whh,
    const float* __restrict__ bih, const float* __restrict__ bhh,
    const __hip_bfloat16* __restrict__ giRd, __hip_bfloat16* __restrict__ giWr,
    u64* __restrict__ hB0, u64* __restrict__ hB1,
    __hip_bfloat16* __restrict__ encB, u32* __restrict__ cnt, int t0, int t0n)
{
    __shared__ float lds[4352];   // 17.4 KB: stage 4096 + pack 256
    const int tid = threadIdx.x;
    const int blk = blockIdx.x;

    if (blk >= 192) {     // produce gi for next chunk on spare blocks
        if (t0n >= 0) {
            for (int tile = blk - 192; tile < 36 * CH; tile += 64) {
                const int j0 = (tile % 36) * 64;
                const int tc = tile / 36;
                giTile(x, Wih, giWr, t0n + tc, tc, j0, lds, lds + 1024, tid);
                __syncthreads();
            }
        }
        return;
    }

    const int b = tid & 63;
    const int w = tid >> 6;
    const int j = __builtin_amdgcn_readfirstlane(blk * 4 + w);
    const float* whr = Whh + (size_t)j * D;
    const float* whz = Whh + (size_t)(768 + j) * D;
    const float* whn = Whh + (size_t)(1536 + j) * D;
    const float bir = bih[j] + bhh[j];
    const float biz = bih[768 + j] + bhh[768 + j];
    const float bin_ = bih[1536 + j];
    const float bhn  = bhh[1536 + j];

    // h_old register (chunk start: t0 even -> current buffer is hB0)
    float hreg = bfu(dev_load_u64(hB0 + blk * 64 + b), w);

    u32 tgt = 0;
    for (int tt = 0; tt < CH; ++tt) {
        const int t = t0 + tt;
        const u64* hc = (t & 1) ? hB1 : hB0;
        u64*       hn_buf = (t & 1) ? hB0 : hB1;

        float ahr = 0.f, ahz = 0.f, ahn = 0.f;
        for (int kc = 0; kc < D; kc += 64) {
            #pragma unroll
            for (int i = 0; i < 4; ++i) {
                const int idx = tid + 256 * i;
                const int ql = idx >> 6, bb = idx & 63;
                const u64 e = dev_load_u64(hc + ((kc >> 2) + ql) * 64 + bb);
                lds[(ql * 4 + 0) * 64 + bb] = bfu(e, 0);
                lds[(ql * 4 + 1) * 64 + bb] = bfu(e, 1);
                lds[(ql * 4 + 2) * 64 + bb] = bfu(e, 2);
                lds[(ql * 4 + 3) * 64 + bb] = bfu(e, 3);
            }
            __syncthreads();
            #pragma unroll
            for (int kk = 0; kk < 64; kk += 4) {
                const float4 v3 = *(const float4*)(whr + kc + kk);
                const float4 v4 = *(const float4*)(whz + kc + kk);
                const float4 v5 = *(const float4*)(whn + kc + kk);
                const float h0 = lds[(kk + 0) * 64 + b];
                const float h1 = lds[(kk + 1) * 64 + b];
                const float h2 = lds[(kk + 2) * 64 + b];
                const float h3 = lds[(kk + 3) * 64 + b];
                DOT4(ahr, v3, h0, h1, h2, h3);
                DOT4(ahz, v4, h0, h1, h2, h3);
                DOT4(ahn, v5, h0, h1, h2, h3);
            }
            __syncthreads();
        }
        const float gir = __bfloat162float(giRd[((size_t)tt * G3 + j) * 64 + b]);
        const float giz = __bfloat162float(giRd[((size_t)tt * G3 + 768 + j) * 64 + b]);
        const float gin = __bfloat162float(giRd[((size_t)tt * G3 + 1536 + j) * 64 + b]);
        const float r = sigf(gir + ahr + bir);
        const float z = sigf(giz + ahz + biz);
        const float n = tanhfast(gin + bin_ + r * (ahn + bhn));
        const float hn = (1.f - z) * n + z * hreg;
        hreg = hn;
        encB[((size_t)b * SEQ + t) * D + j] = __float2bfloat16(hn);
        // pack broadcast bf16: pk[b*4 + w]
        {
            __hip_bfloat16 hb = __float2bfloat16(hn);
            ((unsigned short*)(lds + 4096))[b * 4 + w] = *(unsigned short*)&hb;
        }
        __syncthreads();
        if (tid < 64) dev_store_u64(hn_buf + blk * 64 + tid, ((u64*)(lds + 4096))[tid]);
        pbar(cnt, tgt, 192);
    }
}

// ---------------- kGemmMem (R4-proven) ----------------
__global__ __launch_bounds__(256) void kGemmMem(
    const __hip_bfloat16* __restrict__ encB, const float* __restrict__ mW,
    const float* __restrict__ mb, __hip_bfloat16* __restrict__ memB)
{
    __shared__ float As[16 * 64];
    __shared__ float Bs[16 * 64];
    const int tid = threadIdx.x;
    const int m0 = blockIdx.y * 64, n0 = blockIdx.x * 64;
    const int lr = tid >> 2;
    const int lk = (tid & 3) * 4;
    const int tm = (tid >> 4) * 4;
    const int tn = (tid & 15) * 4;
    float acc[4][4];
    #pragma unroll
    for (int i = 0; i < 4; ++i)
        #pragma unroll
        for (int j = 0; j < 4; ++j) acc[i][j] = 0.f;
    for (int kc = 0; kc < D; kc += 16) {
        const uint2 ua = *(const uint2*)(encB + (size_t)(m0 + lr) * D + kc + lk);
        float a0, a1, a2, a3;
        bf2x(ua.x, a0, a1); bf2x(ua.y, a2, a3);
        const float4 b4 = *(const float4*)(mW + (size_t)(n0 + lr) * D + kc + lk);
        As[(lk + 0) * 64 + lr] = a0; As[(lk + 1) * 64 + lr] = a1;
        As[(lk + 2) * 64 + lr] = a2; As[(lk + 3) * 64 + lr] = a3;
        Bs[(lk + 0) * 64 + lr] = b4.x; Bs[(lk + 1) * 64 + lr] = b4.y;
        Bs[(lk + 2) * 64 + lr] = b4.z; Bs[(lk + 3) * 64 + lr] = b4.w;
        __syncthreads();
        #pragma unroll
        for (int k = 0; k < 16; ++k) {
            const float4 av = *(const float4*)(As + k * 64 + tm);
            const float4 bv = *(const float4*)(Bs + k * 64 + tn);
            acc[0][0] = fmaf(av.x, bv.x, acc[0][0]); acc[0][1] = fmaf(av.x, bv.y, acc[0][1]);
            acc[0][2] = fmaf(av.x, bv.z, acc[0][2]); acc[0][3] = fmaf(av.x, bv.w, acc[0][3]);
            acc[1][0] = fmaf(av.y, bv.x, acc[1][0]); acc[1][1] = fmaf(av.y, bv.y, acc[1][1]);
            acc[1][2] = fmaf(av.y, bv.z, acc[1][2]); acc[1][3] = fmaf(av.y, bv.w, acc[1][3]);
            acc[2][0] = fmaf(av.z, bv.x, acc[2][0]); acc[2][1] = fmaf(av.z, bv.y, acc[2][1]);
            acc[2][2] = fmaf(av.z, bv.z, acc[2][2]); acc[2][3] = fmaf(av.z, bv.w, acc[2][3]);
            acc[3][0] = fmaf(av.w, bv.x, acc[3][0]); acc[3][1] = fmaf(av.w, bv.y, acc[3][1]);
            acc[3][2] = fmaf(av.w, bv.z, acc[3][2]); acc[3][3] = fmaf(av.w, bv.w, acc[3][3]);
        }
        __syncthreads();
    }
    const float bb0 = mb[n0 + tn + 0], bb1 = mb[n0 + tn + 1];
    const float bb2 = mb[n0 + tn + 2], bb3 = mb[n0 + tn + 3];
    #pragma unroll
    for (int i = 0; i < 4; ++i) {
        __hip_bfloat16* row = memB + (size_t)(m0 + tm + i) * D + n0 + tn;
        row[0] = __float2bfloat16(acc[i][0] + bb0);
        row[1] = __float2bfloat16(acc[i][1] + bb1);
        row[2] = __float2bfloat16(acc[i][2] + bb2);
        row[3] = __float2bfloat16(acc[i][3] + bb3);
    }
}

// ---------------- kDecP: persistent decoder (256 blocks x 512 threads) ----------------
__global__ __launch_bounds__(512, 2) void kDecP(
    const float* __restrict__ qW, const float* __restrict__ qb,
    const __hip_bfloat16* __restrict__ memB, const __hip_bfloat16* __restrict__ encB,
    const float* __restrict__ pW, const float* __restrict__ pb,
    const float* __restrict__ dWhh, const float* __restrict__ Wc, const float* __restrict__ W0,
    const float* __restrict__ dbih, const float* __restrict__ dbhh,
    const float* __restrict__ tW, const float* __restrict__ tb,
    u64* __restrict__ hBd0, u64* __restrict__ hBd1,
    float* __restrict__ qT2, float* __restrict__ ctx0, float* __restrict__ ctx1,
    float* __restrict__ se0, float* __restrict__ se1,
    float* __restrict__ last0, float* __restrict__ last1,
    float* __restrict__ out, u32* __restrict__ cnt)
{
    __shared__ float lds[8704];      // 34.8 KB
    const int tid = threadIdx.x;
    const int blk = blockIdx.x;
    const int b = tid & 63;
    const int wv = tid >> 6;
    u32 tgt = 0;
    float hreg = 0.f;                // C-phase h_old (thread owns (j,b))
    const float tbv = tb[0];

    for (int t = 0; t < TDEC; ++t) {
        const u64* hBc = (t & 1) ? hBd1 : hBd0;
        u64*       hBn = (t & 1) ? hBd0 : hBd1;
        float* ctxC = (t & 1) ? ctx1 : ctx0;
        float* ctxN = (t & 1) ? ctx0 : ctx1;
        float* seC  = (t & 1) ? se1 : se0;
        float* seN  = (t & 1) ? se0 : se1;
        float* lastC = (t & 1) ? last1 : last0;
        float* lastN = (t & 1) ? last0 : last1;

        // ---- Phase Q: blk<192 compute q (4 j, 256 active); blk>=192 zero next buffers
        if (blk < 192) {
            float acc = 0.f;
            const int jq = __builtin_amdgcn_readfirstlane(blk * 4 + (wv & 3));
            const float* wrow = qW + (size_t)jq * D;
            for (int kc = 0; kc < D; kc += 64) {
                #pragma unroll
                for (int i = 0; i < 2; ++i) {
                    const int idx = tid + 512 * i;
                    const int ql = idx >> 6, bb = idx & 63;
                    const u64 e = dev_load_u64(hBc + ((kc >> 2) + ql) * 64 + bb);
                    lds[(ql * 4 + 0) * 64 + bb] = bfu(e, 0);
                    lds[(ql * 4 + 1) * 64 + bb] = bfu(e, 1);
                    lds[(ql * 4 + 2) * 64 + bb] = bfu(e, 2);
                    lds[(ql * 4 + 3) * 64 + bb] = bfu(e, 3);
                }
                __syncthreads();
                if (tid < 256) {
                    #pragma unroll
                    for (int kk = 0; kk < 64; kk += 4) {
                        const float4 w4 = *(const float4*)(wrow + kc + kk);
                        acc = fmaf(w4.x, lds[(kk + 0) * 64 + b], acc);
                        acc = fmaf(w4.y, lds[(kk + 1) * 64 + b], acc);
                        acc = fmaf(w4.z, lds[(kk + 2) * 64 + b], acc);
                        acc = fmaf(w4.w, lds[(kk + 3) * 64 + b], acc);
                    }
                }
                __syncthreads();
            }
            if (tid < 256) lds[4096 + b * 4 + wv] = acc + qb[jq];
            __syncthreads();
            if (tid < 128) {
                const int r = tid >> 1, part = tid & 1;
                union { float f[2]; u64 u; } c;
                c.f[0] = lds[4096 + r * 4 + part * 2];
                c.f[1] = lds[4096 + r * 4 + part * 2 + 1];
                dev_store_u64((u64*)(qT2 + (size_t)r * D + blk * 4 + part * 2), c.u);
            }
        } else {
            const int base = (blk - 192) * 768;
            for (int i = tid; i < 768; i += 512) dev_store_f32(ctxN + base + i, 0.f);
            if (blk == 192 && tid < 64) dev_store_f32(seN + tid, 0.f);
            if (blk == 193 && tid < 64) dev_store_f32(lastN + tid, tbv);
        }
        pbar(cnt, tgt, 256);

        // ---- Phase A: attention, all 256 blocks (b=blk&63, ch=blk>>6), 75 rows, 8 waves
        {
            const int ab = blk & 63;
            const int ch = blk >> 6;
            const int s0 = ch * 75;
            float* s_q  = lds;
            float* s_pw = lds + 768;
            float* s_cx = lds + 1536;
            float* s_se = lds + 2304;
            for (int i = tid; i < 384; i += 512) {
                union { u64 u; float f[2]; } c;
                c.u = dev_load_u64((const u64*)(qT2 + (size_t)ab * D + 2 * i));
                s_q[2 * i] = c.f[0]; s_q[2 * i + 1] = c.f[1];
            }
            for (int i = tid; i < 768; i += 512) { s_pw[i] = pW[i]; s_cx[i] = 0.f; }
            if (tid == 0) s_se[0] = 0.f;
            __syncthreads();
            const int lane = tid & 63;
            float cacc[12];
            #pragma unroll
            for (int i = 0; i < 12; ++i) cacc[i] = 0.f;
            float seacc = 0.f;
            const float pbv = pb[0];
            for (int s = s0 + wv; s < s0 + 75; s += 8) {
                const __hip_bfloat16* mrow = memB + ((size_t)ab * SEQ + s) * D;
                const __hip_bfloat16* erow = encB + ((size_t)ab * SEQ + s) * D;
                float lp = 0.f;
                #pragma unroll
                for (int g = 0; g < 3; ++g) {
                    const int d0 = g * 256 + lane * 4;
                    const uint2 mu = *(const uint2*)(mrow + d0);
                    float m0, m1, m2, m3;
                    bf2x(mu.x, m0, m1); bf2x(mu.y, m2, m3);
                    const float4 qv = *(const float4*)(s_q + d0);
                    const float4 pv = *(const float4*)(s_pw + d0);
                    lp = fmaf(pv.x, tanhfast(m0 + qv.x), lp);
                    lp = fmaf(pv.y, tanhfast(m1 + qv.y), lp);
                    lp = fmaf(pv.z, tanhfast(m2 + qv.z), lp);
                    lp = fmaf(pv.w, tanhfast(m3 + qv.w), lp);
                }
                #pragma unroll
                for (int o = 32; o > 0; o >>= 1) lp += __shfl_xor(lp, o, 64);
                const float e = __expf(lp + pbv);     // identical on all 64 lanes
                seacc += e;
                #pragma unroll
                for (int g = 0; g < 3; ++g) {
                    const int d0 = g * 256 + lane * 4;
                    const uint2 eu = *(const uint2*)(erow + d0);
                    float e0, e1, e2, e3;
                    bf2x(eu.x, e0, e1); bf2x(eu.y, e2, e3);
                    cacc[g * 4 + 0] = fmaf(e, e0, cacc[g * 4 + 0]);
                    cacc[g * 4 + 1] = fmaf(e, e1, cacc[g * 4 + 1]);
                    cacc[g * 4 + 2] = fmaf(e, e2, cacc[g * 4 + 2]);
                    cacc[g * 4 + 3] = fmaf(e, e3, cacc[g * 4 + 3]);
                }
            }
            #pragma unroll
            for (int g = 0; g < 3; ++g) {
                const int d0 = g * 256 + lane * 4;
                atomicAdd(&s_cx[d0 + 0], cacc[g * 4 + 0]);
                atomicAdd(&s_cx[d0 + 1], cacc[g * 4 + 1]);
                atomicAdd(&s_cx[d0 + 2], cacc[g * 4 + 2]);
                atomicAdd(&s_cx[d0 + 3], cacc[g * 4 + 3]);
            }
            if (lane == 0) atomicAdd(&s_se[0], seacc);
            __syncthreads();
            for (int i = tid; i < 768; i += 512) dev_atomic_add_f32(ctxC + (size_t)i * 64 + ab, s_cx[i]);
            if (tid == 0) dev_atomic_add_f32(seC + ab, s_se[0]);
        }
        pbar(cnt, tgt, 256);

        // ---- Phase C: GRU cell + pred, blk<192 (4 j, 256 active)
        if (blk < 192) {
            const int jc = __builtin_amdgcn_readfirstlane(blk * 4 + (wv & 3));
            const float* wcr = Wc + (size_t)jc * D;
            const float* wcz = Wc + (size_t)(768 + jc) * D;
            const float* wcn = Wc + (size_t)(1536 + jc) * D;
            const float* whr = dWhh + (size_t)jc * D;
            const float* whz = dWhh + (size_t)(768 + jc) * D;
            const float* whn = dWhh + (size_t)(1536 + jc) * D;
            float cir = 0.f, ciz = 0.f, cin_ = 0.f, ahr = 0.f, ahz = 0.f, ahn = 0.f;
            float* lds_h = lds;
            float* lds_c = lds + 4096;
            for (int kc = 0; kc < D; kc += 64) {
                #pragma unroll
                for (int i = 0; i < 2; ++i) {
                    const int idx = tid + 512 * i;
                    const int ql = idx >> 6, bb = idx & 63;
                    const u64 e = dev_load_u64(hBc + ((kc >> 2) + ql) * 64 + bb);
                    lds_h[(ql * 4 + 0) * 64 + bb] = bfu(e, 0);
                    lds_h[(ql * 4 + 1) * 64 + bb] = bfu(e, 1);
                    lds_h[(ql * 4 + 2) * 64 + bb] = bfu(e, 2);
                    lds_h[(ql * 4 + 3) * 64 + bb] = bfu(e, 3);
                }
                #pragma unroll
                for (int i = 0; i < 4; ++i) {
                    const int idx = tid + 512 * i;
                    const int kl = idx >> 5, bp = (idx & 31) * 2;
                    union { u64 u; float f[2]; } c;
                    c.u = dev_load_u64((const u64*)(ctxC + (size_t)(kc + kl) * 64 + bp));
                    lds_c[kl * 64 + bp] = c.f[0];
                    lds_c[kl * 64 + bp + 1] = c.f[1];
                }
                __syncthreads();
                if (tid < 256) {
                    #pragma unroll
                    for (int kk = 0; kk < 64; kk += 4) {
                        const float4 v0 = *(const float4*)(wcr + kc + kk);
                        const float4 v1 = *(const float4*)(wcz + kc + kk);
                        const float4 v2 = *(const float4*)(wcn + kc + kk);
                        const float4 v3 = *(const float4*)(whr + kc + kk);
                        const float4 v4 = *(const float4*)(whz + kc + kk);
                        const float4 v5 = *(const float4*)(whn + kc + kk);
                        const float c0 = lds_c[(kk + 0) * 64 + b];
                        const float c1 = lds_c[(kk + 1) * 64 + b];
                        const float c2 = lds_c[(kk + 2) * 64 + b];
                        const float c3 = lds_c[(kk + 3) * 64 + b];
                        const float h0 = lds_h[(kk + 0) * 64 + b];
                        const float h1 = lds_h[(kk + 1) * 64 + b];
                        const float h2 = lds_h[(kk + 2) * 64 + b];
                        const float h3 = lds_h[(kk + 3) * 64 + b];
                        DOT4(cir, v0, c0, c1, c2, c3);
                        DOT4(ciz, v1, c0, c1, c2, c3);
                        DOT4(cin_, v2, c0, c1, c2, c3);
                        DOT4(ahr, v3, h0, h1, h2, h3);
                        DOT4(ahz, v4, h0, h1, h2, h3);
                        DOT4(ahn, v5, h0, h1, h2, h3);
                    }
                }
                __syncthreads();
            }
            if (tid < 256) {
                const float se = dev_load_f32(seC + b);
                const float inv = 1.f / se;
                const float lst = dev_load_f32(lastC + b);
                const float gir = cir * inv + W0[jc] * lst + dbih[jc];
                const float giz = ciz * inv + W0[768 + jc] * lst + dbih[768 + jc];
                const float gin = cin_ * inv + W0[1536 + jc] * lst + dbih[1536 + jc];
                const float r = sigf(gir + ahr + dbhh[jc]);
                const float z = sigf(giz + ahz + dbhh[768 + jc]);
                const float n = tanhfast(gin + r * (ahn + dbhh[1536 + jc]));
                const float hn = (1.f - z) * n + z * hreg;
                hreg = hn;
                lds[8192 + wv * 64 + b] = tW[jc] * hn;
                __hip_bfloat16 hb = __float2bfloat16(hn);
                ((unsigned short*)(lds + 8448))[b * 4 + wv] = *(unsigned short*)&hb;
            }
            __syncthreads();
            if (tid < 64) {
                const float p = lds[8192 + tid] + lds[8192 + 64 + tid]
                              + lds[8192 + 128 + tid] + lds[8192 + 192 + tid];
                atomicAdd(&out[(size_t)tid * TDEC + t], p);
                dev_atomic_add_f32(lastN + tid, p);
                dev_store_u64(hBn + blk * 64 + tid, ((u64*)(lds + 8448))[tid]);
            }
        }
        pbar(cnt, tgt, 256);
    }
}

// ---------------- launch ----------------
extern "C" void kernel_launch(void* const* d_in, const int* in_sizes, int n_in,
                              void* d_out, int out_size, void* d_ws, size_t ws_size,
                              hipStream_t stream) {
    const float* x    = (const float*)d_in[0];
    const float* eWih = (const float*)d_in[1];
    const float* eWhh = (const float*)d_in[2];
    const float* ebih = (const float*)d_in[3];
    const float* ebhh = (const float*)d_in[4];
    const float* dWih = (const float*)d_in[5];
    const float* dWhh = (const float*)d_in[6];
    const float* dbih = (const float*)d_in[7];
    const float* dbhh = (const float*)d_in[8];
    const float* qW   = (const float*)d_in[9];
    const float* qb   = (const float*)d_in[10];
    const float* mW   = (const float*)d_in[11];
    const float* mb   = (const float*)d_in[12];
    const float* pW   = (const float*)d_in[13];
    const float* pb   = (const float*)d_in[14];
    const float* tW   = (const float*)d_in[15];
    const float* tb   = (const float*)d_in[16];
    float* out = (float*)d_out;

    char* w = (char*)d_ws;
    auto alloc = [&](size_t bytes) -> char* {
        char* p = w; w += (bytes + 255) & ~(size_t)255; return p;
    };
    // ~67 MB total
    float* Wc   = (float*)alloc((size_t)G3 * D * 4);
    float* W0   = (float*)alloc((size_t)G3 * 4);
    __hip_bfloat16* encB = (__hip_bfloat16*)alloc((size_t)BS * SEQ * D * 2);
    char* memRegion = alloc((size_t)BS * SEQ * D * 2);      // memB; giA/giB alias inside
    __hip_bfloat16* memB = (__hip_bfloat16*)memRegion;
    __hip_bfloat16* giA  = (__hip_bfloat16*)memRegion;
    __hip_bfloat16* giB  = (__hip_bfloat16*)(memRegion + (size_t)CH * G3 * 64 * 2);
    u64* hBe0 = (u64*)alloc(192 * 64 * 8);
    u64* hBe1 = (u64*)alloc(192 * 64 * 8);
    u64* hBd0 = (u64*)alloc(192 * 64 * 8);
    u64* hBd1 = (u64*)alloc(192 * 64 * 8);
    float* qT2  = (float*)alloc((size_t)BS * D * 4);
    float* ctx0 = (float*)alloc((size_t)D * 64 * 4);
    float* ctx1 = (float*)alloc((size_t)D * 64 * 4);
    float* se0  = (float*)alloc(256);
    float* se1  = (float*)alloc(256);
    float* last0 = (float*)alloc(256);
    float* last1 = (float*)alloc(256);
    u32* cnt = (u32*)alloc(128 * sizeof(u32));   // 6x8 enc + 8 dec

    kPrep<<<512, 256, 0, stream>>>(dWih, tb, Wc, W0, hBe0, hBe1, hBd0, hBd1,
                                   ctx0, se0, last0, out, cnt);
    kGi0<<<dim3(36, CH), 256, 0, stream>>>(x, eWih, giA);
    for (int c = 0; c < SEQ / CH; ++c) {
        __hip_bfloat16* giRd = (c & 1) ? giB : giA;
        __hip_bfloat16* giWr = (c & 1) ? giA : giB;
        const int t0n = (c < SEQ / CH - 1) ? (c + 1) * CH : -1;
        kEncP<<<256, 256, 0, stream>>>(x, eWih, eWhh, ebih, ebhh, giRd, giWr,
                                       hBe0, hBe1, encB, cnt + c * 8, c * CH, t0n);
    }
    kGemmMem<<<dim3(12, 300), 256, 0, stream>>>(encB, mW, mb, memB);
    kDecP<<<256, 512, 0, stream>>>(qW, qb, memB, encB, pW, pb, dWhh, Wc, W0, dbih, dbhh,
                                   tW, tb, hBd0, hBd1, qT2, ctx0, ctx1, se0, se1,
                                   last0, last1, out, cnt + 48);
}